// Round 18
// baseline (102.591 us; speedup 1.0000x reference)
//
#include <hip/hip_runtime.h>
#include <math.h>

// Problem constants (from reference)
constexpr int B_  = 16;
constexpr int LQ_ = 1024;
constexpr int LK_ = 4096;
constexpr int D_  = 256;
constexpr float HALF_BW_F = 64.0f;         // 128 // 2
constexpr float SCALE = 0.0625f;           // (D^-0.25)^2 = 1/sqrt(256)

// native clang vector types
typedef float  fx4    __attribute__((ext_vector_type(4)));
typedef short  bf16x8 __attribute__((ext_vector_type(8)));
typedef float  f32x4v __attribute__((ext_vector_type(4)));

constexpr int ROWS_PER_WAVE = 16;          // one MFMA M-tile
constexpr int ROWS_PER_BLK  = 64;          // 4 waves
constexpr int NUNIT = (B_ * LQ_) / ROWS_PER_BLK;   // 256 compute units
constexpr int NXCD  = 8;
constexpr int UNIT_PER_XCD = NUNIT / NXCD; // 32
constexpr int KSPAN = 192;                 // wave key span <= 15*4+129 = 189
constexpr int NT    = 12;                  // key tiles of 16

__device__ __forceinline__ unsigned short f2bf(float f) {
    unsigned int u = __float_as_uint(f);
    return (unsigned short)((u + 0x7FFFu + ((u >> 16) & 1u)) >> 16);  // RNE
}
__device__ __forceinline__ bf16x8 pack8(float4 a, float4 b) {
    bf16x8 r;
    r[0] = (short)f2bf(a.x); r[1] = (short)f2bf(a.y);
    r[2] = (short)f2bf(a.z); r[3] = (short)f2bf(a.w);
    r[4] = (short)f2bf(b.x); r[5] = (short)f2bf(b.y);
    r[6] = (short)f2bf(b.z); r[7] = (short)f2bf(b.w);
    return r;
}
// reductions within a 16-lane group (xor offsets stay inside the group)
__device__ __forceinline__ float grp16_max(float v) {
    #pragma unroll
    for (int off = 8; off > 0; off >>= 1)
        v = fmaxf(v, __shfl_xor(v, off, 64));
    return v;
}
__device__ __forceinline__ float grp16_sum(float v) {
    #pragma unroll
    for (int off = 8; off > 0; off >>= 1)
        v += __shfl_xor(v, off, 64);
    return v;
}

// MFMA rewrite: one wave owns 16 consecutive q-rows; scores computed as
// S[16 x 192] via mfma_f32_16x16x32_bf16 (12 key-tiles x 8 K-chunks, fp32
// accumulate). Kills the per-key serial chain (DPP reduces, l==15 LDS
// stores) that kept the VALU score loop at ~700cyc/iter across R12-R17,
// and gives 4x K-reuse (573 -> 197 MB logical reads). bf16 input rounding
// -> weight absmax ~0.01 << 0.108 threshold. Fill blocks (zero stripes +
// V copy) unchanged. A-frag: row=lane&15, k=(lane>>4)*8+j; B-frag:
// col=lane&15, k=(lane>>4)*8+j; C/D: col=lane&15, row=(lane>>4)*4+reg
// [m89-verified].
__global__ __launch_bounds__(256, 2) void stripe_attn_kernel(
    const float* __restrict__ Q, const float* __restrict__ K,
    const float* __restrict__ V,
    const int* __restrict__ qlen, const int* __restrict__ klen,
    float* __restrict__ Wout, float* __restrict__ Vout)
{
    const int Bid  = blockIdx.x;
    const int xcd  = Bid & 7;
    const int type = (Bid >> 3) & 1;
    const int slot = Bid >> 4;                       // 0..31 within XCD
    const int cu_u = xcd * UNIT_PER_XCD + slot;      // unit 0..255
    const int tid  = threadIdx.x;
    const int lane = tid & 63;
    const int wave = tid >> 6;
    const int row0 = cu_u * ROWS_PER_BLK + wave * ROWS_PER_WAVE; // wave's 16 rows
    const int b    = row0 >> 10;                     // one batch per block
    const int qi0  = row0 & (LQ_ - 1);

    const int   key_len = klen[b];
    const float slope   = (float)key_len / (float)qlen[b];   // fp32 div (ref)

    if (type == 1) {
        // ================= FILL BLOCK: pure store pump (16 rows/wave) ======
        const float* vs = V    + (size_t)row0 * 1024;
        float*       vd = Vout + (size_t)row0 * 1024;
        #pragma unroll
        for (int it = 0; it < 64; ++it) {
            const int o = (it * 64 + lane) * 4;
            fx4 t = __builtin_nontemporal_load((const fx4*)(vs + o));
            __builtin_nontemporal_store(t, (fx4*)(vd + o));
        }
        const fx4 z4 = {0.f, 0.f, 0.f, 0.f};
        #pragma unroll
        for (int r = 0; r < 16; ++r) {
            const float center = (float)(qi0 + r) * slope;
            int lo = (int)ceilf(center - HALF_BW_F); if (lo < 0) lo = 0;
            int hi = (int)floorf(center + HALF_BW_F); if (hi > key_len - 1) hi = key_len - 1;
            const int s_lo = lo >> 8, s_hi = hi >> 8;
            float* base = Wout + (size_t)(row0 + r) * LK_;
            #pragma unroll
            for (int j = 0; j < 16; ++j) {
                if (j < s_lo || j > s_hi)
                    __builtin_nontemporal_store(z4, (fx4*)(base + (j * 64 + lane) * 4));
            }
        }
        return;
    }

    // ================= COMPUTE BLOCK =================
    __shared__ float s_sc[4][ROWS_PER_WAVE][KSPAN];  // 48 KB: weights by key-lo_w

    // wave-uniform key band (union over the 16 rows)
    int lo_w = (int)ceilf((float)qi0 * slope - HALF_BW_F);
    if (lo_w < 0) lo_w = 0;
    int hi_w = (int)floorf((float)(qi0 + 15) * slope + HALF_BW_F);
    if (hi_w > key_len - 1) hi_w = key_len - 1;
    const int nt = (hi_w - lo_w) / 16 + 1;           // <= 12

    const int col = lane & 15;                       // key-within-tile / q-row (A)
    const int kg  = lane >> 4;                       // K-chunk sub-index

    // ---- Q A-fragments: lane holds Q[qi0 + col][kc*32 + kg*8 + 0..7] ----
    const float* qb = Q + ((size_t)b * LQ_ + qi0 + col) * D_ + kg * 8;
    bf16x8 qf[8];
    #pragma unroll
    for (int kc = 0; kc < 8; ++kc) {
        const float4 u = *(const float4*)(qb + kc * 32);
        const float4 v = *(const float4*)(qb + kc * 32 + 4);
        qf[kc] = pack8(u, v);
    }

    // ---- scores: 12 key-tiles x 8 chunks of mfma, fp32 accumulate ----
    const float* kb = K + (size_t)b * LK_ * D_ + kg * 8;
    f32x4v acc[NT];
    #pragma unroll
    for (int t = 0; t < NT; ++t) acc[t] = (f32x4v){0.f, 0.f, 0.f, 0.f};

    #pragma unroll
    for (int t = 0; t < NT; ++t) {
        if (t < nt) {                                // wave-uniform guard
            const int key  = lo_w + t * 16 + col;
            const int keyc = (key <= hi_w) ? key : hi_w;   // clamp: in-batch
            const float* kp = kb + (size_t)keyc * D_;
            float4 u[8], w[8];
            #pragma unroll
            for (int kc = 0; kc < 8; ++kc) {
                u[kc] = *(const float4*)(kp + kc * 32);
                w[kc] = *(const float4*)(kp + kc * 32 + 4);
            }
            #pragma unroll
            for (int kc = 0; kc < 8; ++kc) {
                const bf16x8 kf = pack8(u[kc], w[kc]);
                acc[t] = __builtin_amdgcn_mfma_f32_16x16x32_bf16(qf[kc], kf, acc[t], 0, 0, 0);
            }
        }
    }

    // ---- softmax: lane owns rows (kg*4 + r), key col, across nt tiles ----
    #pragma unroll
    for (int r = 0; r < 4; ++r) {
        const int rg = kg * 4 + r;                   // row within unit
        const float center = (float)(qi0 + rg) * slope;
        int klo = (int)ceilf(center - HALF_BW_F); if (klo < 0) klo = 0;
        int khi = (int)floorf(center + HALF_BW_F); if (khi > key_len - 1) khi = key_len - 1;

        float v[NT];
        #pragma unroll
        for (int t = 0; t < NT; ++t) {
            const int key = lo_w + t * 16 + col;
            v[t] = (t < nt && key >= klo && key <= khi) ? acc[t][r] * SCALE : -INFINITY;
        }
        float mx = v[0];
        #pragma unroll
        for (int t = 1; t < NT; ++t) mx = fmaxf(mx, v[t]);
        mx = grp16_max(mx);

        float e[NT], ssum = 0.f;
        #pragma unroll
        for (int t = 0; t < NT; ++t) { e[t] = __expf(v[t] - mx); ssum += e[t]; }
        ssum = grp16_sum(ssum);
        const float inv = 1.0f / ssum;

        #pragma unroll
        for (int t = 0; t < NT; ++t)
            if (t < nt) s_sc[wave][rg][t * 16 + col] = e[t] * inv;  // 0 outside band
    }
    // within-wave LDS write->read: in-order, no barrier needed

    // ---- band stripes (<=2 per row; fill partner wrote the rest) ----
    #pragma unroll
    for (int r = 0; r < 16; ++r) {
        const float center = (float)(qi0 + r) * slope;
        int klo = (int)ceilf(center - HALF_BW_F); if (klo < 0) klo = 0;
        int khi = (int)floorf(center + HALF_BW_F); if (khi > key_len - 1) khi = key_len - 1;
        const int s_lo = klo >> 8, s_hi = khi >> 8;
        float* base = Wout + (size_t)(row0 + r) * LK_;
        const float* sr = &s_sc[wave][r][0];         // indexed by key - lo_w
        for (int j = s_lo; j <= s_hi; ++j) {         // <=2 iterations
            const int c0 = (j * 64 + lane) * 4;
            float w[4] = {0.f, 0.f, 0.f, 0.f};
            if (c0 + 3 >= klo && c0 <= khi) {
                #pragma unroll
                for (int i = 0; i < 4; ++i) {
                    const int c = c0 + i;
                    if (c >= klo && c <= khi) w[i] = sr[c - lo_w];
                }
            }
            fx4 w4; w4.x = w[0]; w4.y = w[1]; w4.z = w[2]; w4.w = w[3];
            __builtin_nontemporal_store(w4, (fx4*)(base + c0));
        }
    }
}

extern "C" void kernel_launch(void* const* d_in, const int* in_sizes, int n_in,
                              void* d_out, int out_size, void* d_ws, size_t ws_size,
                              hipStream_t stream) {
    // inputs (setup_inputs order): query, key, value, mask, query_lengths, key_lengths
    const float* Q    = (const float*)d_in[0];
    const float* K    = (const float*)d_in[1];
    const float* V    = (const float*)d_in[2];
    const int*   qlen = (const int*)d_in[4];
    const int*   klen = (const int*)d_in[5];

    float* Wout = (float*)d_out;
    const size_t W_ELEMS = (size_t)B_ * LQ_ * LK_;        // 67,108,864
    float* Vout = Wout + W_ELEMS;

    stripe_attn_kernel<<<dim3(2 * NUNIT), dim3(256), 0, stream>>>(
        Q, K, V, qlen, klen, Wout, Vout);
}